// Round 2
// baseline (1530.051 us; speedup 1.0000x reference)
//
#include <hip/hip_runtime.h>
#include <cstdint>

#define VOCAB 32000
#define NTOK  1024
#define HS    2048
#define HT    4096

typedef __attribute__((ext_vector_type(8))) short bf16x8;
typedef __attribute__((ext_vector_type(4))) float f32x4;

__device__ __forceinline__ unsigned short f2bf(float f){
  unsigned u = __float_as_uint(f);
  u += 0x7fffu + ((u >> 16) & 1u);   // round-to-nearest-even
  return (unsigned short)(u >> 16);
}
__device__ __forceinline__ unsigned pack2(float a, float b){
  return (unsigned)f2bf(a) | ((unsigned)f2bf(b) << 16);
}
__device__ __forceinline__ float blo(unsigned u){ return __uint_as_float(u << 16); }
__device__ __forceinline__ float bhi(unsigned u){ return __uint_as_float(u & 0xffff0000u); }

// async global -> LDS, 16B per lane. LDS dest must be wave-uniform base (+lane*16 by HW).
__device__ __forceinline__ void async_ld16(const void* g, void* l){
  __builtin_amdgcn_global_load_lds(
      (__attribute__((address_space(1))) void*)(uintptr_t)g,
      (__attribute__((address_space(3))) void*)l,
      16, 0, 0);
}

// ---------------- fp32 -> bf16 (activations AND weights), grid-stride ----------------
__global__ __launch_bounds__(256) void cvt_f32_bf16(const float* __restrict__ in,
                                                    unsigned short* __restrict__ out, int n4){
  const int stride = gridDim.x * 256;
  for (int i = blockIdx.x * 256 + threadIdx.x; i < n4; i += stride){
    float4 v = ((const float4*)in)[i];
    uint2 o;
    o.x = pack2(v.x, v.y);
    o.y = pack2(v.z, v.w);
    ((uint2*)out)[i] = o;
  }
}

// ---------------- GEMM: C[m, v] = sum_k A[m,k]*W[v,k] + bias[v], all bf16 inputs ----------------
// Tile 128x128x32, 256 threads = 4 waves, each wave 64x64 (4x4 MFMA 16x16x32).
// Both operands staged via global_load_lds (linear LDS dest); XOR swizzle realized by
// pre-swizzling the GLOBAL source address (m173 pattern), swizzled ds_read on the way out.
// Swizzle: logical (row, chunk c of 8 bf16) -> prow=row>>1, slot=(((row&1)<<2)|c)^(prow&7),
//          phys byte = prow*128 + slot*16.  (2-way max bank aliasing on ds_read_b128 = free)
// Grid: x = m (8, fastest) -> XCD j owns m-strip j (A stays L2-resident); the 8 sharers of
// each W strip are dispatch-adjacent so LLC serves 7 of 8.
__global__ __launch_bounds__(256, 3) void gemm_logits(
    const unsigned short* __restrict__ A,   // [NTOK, K] bf16
    const unsigned short* __restrict__ W,   // [rows, K] bf16 (chunk base)
    const float* __restrict__ bias,         // chunk base
    unsigned short* __restrict__ C,         // chunk base, row stride VOCAB
    int K)
{
  __shared__ unsigned short lds[2][2][128 * 32];   // [buf][A/B][8KB], 32 KiB total

  const int tid  = threadIdx.x;
  const int lane = tid & 63;
  const int wave = tid >> 6;
  const int m0 = blockIdx.x * 128;
  const int v0 = blockIdx.y * 128;
  const int wm = (wave >> 1) * 64;
  const int wn = (wave & 1) * 64;

  // ---- staging: 2 x 16B per thread per operand; inverse-swizzled global source ----
  int ldsoff[2];                    // wave-uniform LDS byte base per instruction
  const unsigned short* gA[2];
  const unsigned short* gW[2];
#pragma unroll
  for (int q = 0; q < 2; ++q){
    const int s    = (wave * 2 + q) * 64 + lane;   // 16B slot index this lane fills
    const int prow = s >> 3;
    const int slot = (s & 7) ^ (prow & 7);         // inverse of the XOR swizzle
    const int row  = (prow << 1) | (slot >> 2);
    const int col  = (slot & 3) * 8;               // bf16 elements
    gA[q] = A + (size_t)(m0 + row) * K + col;
    gW[q] = W + (size_t)(v0 + row) * K + col;
    ldsoff[q] = (wave * 2 + q) * 1024;             // lane*16 added by HW
  }

  // ---- fragment read offsets (swizzled), loop-invariant ----
  const int ar = lane & 15, kq = lane >> 4;
  int offA[4], offB[4];
#pragma unroll
  for (int i = 0; i < 4; ++i){
    int row  = wm + i * 16 + ar;
    int prow = row >> 1;
    int slot = (((row & 1) << 2) | kq) ^ (prow & 7);
    offA[i] = prow * 128 + slot * 16;
    row  = wn + i * 16 + ar;
    prow = row >> 1;
    slot = (((row & 1) << 2) | kq) ^ (prow & 7);
    offB[i] = prow * 128 + slot * 16;
  }

  const f32x4 zero = {0.f, 0.f, 0.f, 0.f};
  f32x4 acc[4][4];
#pragma unroll
  for (int i = 0; i < 4; i++)
#pragma unroll
    for (int j = 0; j < 4; j++) acc[i][j] = zero;

  auto stage = [&](int buf, int k0){
#pragma unroll
    for (int q = 0; q < 2; ++q){
      async_ld16(gA[q] + k0, (char*)(&lds[buf][0][0]) + ldsoff[q]);
      async_ld16(gW[q] + k0, (char*)(&lds[buf][1][0]) + ldsoff[q]);
    }
  };

  const int NT = K >> 5;
  stage(0, 0);
  __syncthreads();                      // compiler drains vmcnt(0) before s_barrier
  int cur = 0;
  for (int kt = 0; kt < NT; ++kt){
    if (kt + 1 < NT) stage(cur ^ 1, (kt + 1) << 5);   // async loads overlap this tile's compute
    const char* pa = (const char*)(&lds[cur][0][0]);
    const char* pb = (const char*)(&lds[cur][1][0]);
    bf16x8 af[4], bfr[4];
#pragma unroll
    for (int i = 0; i < 4; ++i){
      af[i]  = *(const bf16x8*)(pa + offA[i]);
      bfr[i] = *(const bf16x8*)(pb + offB[i]);
    }
#pragma unroll
    for (int i = 0; i < 4; ++i)
#pragma unroll
      for (int j = 0; j < 4; ++j)
        acc[i][j] = __builtin_amdgcn_mfma_f32_16x16x32_bf16(af[i], bfr[j], acc[i][j], 0, 0, 0);
    __syncthreads();                    // drains next-tile loads; all waves done with buf[cur]
    cur ^= 1;
  }

  // epilogue: C/D layout col = lane&15, row = (lane>>4)*4 + reg  [m89-verified]
  const int rq = lane >> 4;
#pragma unroll
  for (int j = 0; j < 4; j++){
    const int v = v0 + wn + j * 16 + ar;
    const float bv = bias[v];
#pragma unroll
    for (int i = 0; i < 4; i++){
      const int mbase = m0 + wm + i * 16 + rq * 4;
#pragma unroll
      for (int r = 0; r < 4; r++){
        C[(size_t)(mbase + r) * VOCAB + v] = f2bf(acc[i][j][r] + bv);
      }
    }
  }
}

// ---------------- per-row logsumexp over VOCAB ----------------
__global__ __launch_bounds__(256) void row_stats(const unsigned short* __restrict__ L,
                                                 float* __restrict__ lse){
  const int row = blockIdx.x;
  const uint4* p = (const uint4*)(L + (size_t)row * VOCAB);
  float mx = -3.0e38f;
  for (int i = threadIdx.x; i < VOCAB / 8; i += 256){
    uint4 u = p[i];
    float f0 = blo(u.x), f1 = bhi(u.x), f2 = blo(u.y), f3 = bhi(u.y);
    float f4 = blo(u.z), f5 = bhi(u.z), f6 = blo(u.w), f7 = bhi(u.w);
    mx = fmaxf(mx, fmaxf(fmaxf(fmaxf(f0, f1), fmaxf(f2, f3)),
                         fmaxf(fmaxf(f4, f5), fmaxf(f6, f7))));
  }
#pragma unroll
  for (int off = 1; off < 64; off <<= 1) mx = fmaxf(mx, __shfl_xor(mx, off));
  __shared__ float sm[4], ss[4];
  if ((threadIdx.x & 63) == 0) sm[threadIdx.x >> 6] = mx;
  __syncthreads();
  mx = fmaxf(fmaxf(sm[0], sm[1]), fmaxf(sm[2], sm[3]));
  float s = 0.f;
  for (int i = threadIdx.x; i < VOCAB / 8; i += 256){
    uint4 u = p[i];
    s += __expf(blo(u.x) - mx) + __expf(bhi(u.x) - mx)
       + __expf(blo(u.y) - mx) + __expf(bhi(u.y) - mx)
       + __expf(blo(u.z) - mx) + __expf(bhi(u.z) - mx)
       + __expf(blo(u.w) - mx) + __expf(bhi(u.w) - mx);
  }
#pragma unroll
  for (int off = 1; off < 64; off <<= 1) s += __shfl_xor(s, off);
  if ((threadIdx.x & 63) == 0) ss[threadIdx.x >> 6] = s;
  __syncthreads();
  if (threadIdx.x == 0) lse[row] = mx + __logf(ss[0] + ss[1] + ss[2] + ss[3]);
}

// ---------------- JSD + CE, accumulate scalar ----------------
__device__ __forceinline__ float jsd_term(float sl, float tl, float ls, float lt){
  float slp = sl - ls, tlp = tl - lt;
  float sp = __expf(slp), tp = __expf(tlp);
  float lm = __logf(0.5f * (sp + tp));
  return 0.5f * (tp * (tlp - lm) + sp * (slp - lm));  // BETA = 0.5
}

__global__ __launch_bounds__(256) void jsd_ce(
    const unsigned short* __restrict__ Ls, const unsigned short* __restrict__ Lt,
    const float* __restrict__ lse_s, const float* __restrict__ lse_t,
    const int* __restrict__ labels, float* __restrict__ out)
{
  const int row = blockIdx.x;
  const float ls = lse_s[row], lt = lse_t[row];
  const uint4* ps = (const uint4*)(Ls + (size_t)row * VOCAB);
  const uint4* pt = (const uint4*)(Lt + (size_t)row * VOCAB);
  float acc = 0.f;
  for (int i = threadIdx.x; i < VOCAB / 8; i += 256){
    uint4 us = ps[i], ut = pt[i];
    acc += jsd_term(blo(us.x), blo(ut.x), ls, lt) + jsd_term(bhi(us.x), bhi(ut.x), ls, lt);
    acc += jsd_term(blo(us.y), blo(ut.y), ls, lt) + jsd_term(bhi(us.y), bhi(ut.y), ls, lt);
    acc += jsd_term(blo(us.z), blo(ut.z), ls, lt) + jsd_term(bhi(us.z), bhi(ut.z), ls, lt);
    acc += jsd_term(blo(us.w), blo(ut.w), ls, lt) + jsd_term(bhi(us.w), bhi(ut.w), ls, lt);
  }
#pragma unroll
  for (int off = 1; off < 64; off <<= 1) acc += __shfl_xor(acc, off);
  __shared__ float sa[4];
  if ((threadIdx.x & 63) == 0) sa[threadIdx.x >> 6] = acc;
  __syncthreads();
  if (threadIdx.x == 0){
    float tot = sa[0] + sa[1] + sa[2] + sa[3];
    float res = tot * (0.5f / (float)NTOK);          // WEIGHT_SOFT * jsd / N
    int lab = labels[row];
    if (lab != -100){
      float sl_lab = __uint_as_float((unsigned)Ls[(size_t)row * VOCAB + lab] << 16);
      res += (ls - sl_lab) * (0.5f / (float)NTOK);   // WEIGHT_HARD * nll / N
    }
    atomicAdd(out, res);
  }
}

extern "C" void kernel_launch(void* const* d_in, const int* in_sizes, int n_in,
                              void* d_out, int out_size, void* d_ws, size_t ws_size,
                              hipStream_t stream){
  (void)in_sizes; (void)n_in; (void)out_size;
  const float* s_in = (const float*)d_in[0];
  const float* s_w  = (const float*)d_in[1];
  const float* t_in = (const float*)d_in[2];
  const float* t_w  = (const float*)d_in[3];
  const int*   lab  = (const int*)d_in[4];
  const float* s_b  = (const float*)d_in[5];
  const float* t_b  = (const float*)d_in[6];
  float* out = (float*)d_out;

  char* ws = (char*)d_ws;
  size_t off = 0;
  auto alloc = [&](size_t b){ void* p = ws + off; off += (b + 255) & ~(size_t)255; return p; };
  unsigned short* As_bf = (unsigned short*)alloc((size_t)NTOK * HS * 2);
  unsigned short* At_bf = (unsigned short*)alloc((size_t)NTOK * HT * 2);
  unsigned short* Ls    = (unsigned short*)alloc((size_t)NTOK * VOCAB * 2);
  unsigned short* Lt    = (unsigned short*)alloc((size_t)NTOK * VOCAB * 2);
  float* lse_s = (float*)alloc(NTOK * 4);
  float* lse_t = (float*)alloc(NTOK * 4);
  unsigned short* Wbf = (unsigned short*)(ws + off);          // rest of workspace: bf16 W
  const size_t rem = (ws_size > off) ? (ws_size - off) : 0;

  hipMemsetAsync(d_out, 0, sizeof(float), stream);  // d_out is poisoned before each launch

  cvt_f32_bf16<<<NTOK * HS / 4 / 256, 256, 0, stream>>>(s_in, As_bf, NTOK * HS / 4);
  cvt_f32_bf16<<<NTOK * HT / 4 / 256, 256, 0, stream>>>(t_in, At_bf, NTOK * HT / 4);

  // per-side: convert the FULL W to bf16 (one pass), then one full-grid bf16 GEMM.
  // Full grid (2000 blocks) => 4-5 blocks/CU resident vs 2 with chunked 512-block grids,
  // and no cvt->gemm serialization bubbles. Chunked path kept as fallback for small ws.
  auto side = [&](const unsigned short* Abf, const float* Wf, const float* bf,
                  unsigned short* L, int K){
    const size_t need = (size_t)VOCAB * K * 2;
    if (rem >= need){
      int n4 = (int)((size_t)VOCAB * K / 4);
      int cb = (n4 + 255) / 256; if (cb > 8192) cb = 8192;
      cvt_f32_bf16<<<cb, 256, 0, stream>>>(Wf, Wbf, n4);
      gemm_logits<<<dim3(NTOK / 128, VOCAB / 128), 256, 0, stream>>>(Abf, Wbf, bf, L, K);
    } else {
      int crows = 8192;                                  // fallback: chunked (round-1 path)
      size_t maxr = rem / ((size_t)K * 2);
      if ((size_t)crows > maxr) crows = (int)(maxr & ~(size_t)127);
      if (crows < 128) crows = 128;
      for (int vb = 0; vb < VOCAB; vb += crows){
        int rows = VOCAB - vb; if (rows > crows) rows = crows;
        int n4 = (int)((size_t)rows * K / 4);
        int cb = (n4 + 255) / 256; if (cb > 8192) cb = 8192;
        cvt_f32_bf16<<<cb, 256, 0, stream>>>(Wf + (size_t)vb * K, Wbf, n4);
        gemm_logits<<<dim3(NTOK / 128, rows / 128), 256, 0, stream>>>(Abf, Wbf, bf + vb, L + vb, K);
      }
    }
  };
  side(As_bf, s_w, s_b, Ls, HS);
  side(At_bf, t_w, t_b, Lt, HT);

  row_stats<<<NTOK, 256, 0, stream>>>(Ls, lse_s);
  row_stats<<<NTOK, 256, 0, stream>>>(Lt, lse_t);
  jsd_ce<<<NTOK, 256, 0, stream>>>(Ls, Lt, lse_s, lse_t, lab, out);
}

// Round 3
// 1490.046 us; speedup vs baseline: 1.0268x; 1.0268x over previous
//
#include <hip/hip_runtime.h>
#include <cstdint>

#define VOCAB 32000
#define NTOK  1024
#define HS    2048
#define HT    4096

typedef __attribute__((ext_vector_type(8))) short bf16x8;
typedef __attribute__((ext_vector_type(4))) float f32x4;

__device__ __forceinline__ unsigned short f2bf(float f){
  unsigned u = __float_as_uint(f);
  u += 0x7fffu + ((u >> 16) & 1u);   // round-to-nearest-even
  return (unsigned short)(u >> 16);
}
__device__ __forceinline__ unsigned pack2(float a, float b){
  return (unsigned)f2bf(a) | ((unsigned)f2bf(b) << 16);
}
__device__ __forceinline__ float blo(unsigned u){ return __uint_as_float(u << 16); }
__device__ __forceinline__ float bhi(unsigned u){ return __uint_as_float(u & 0xffff0000u); }

// async global -> LDS, 16B per lane. LDS dest must be wave-uniform base (+lane*16 by HW).
__device__ __forceinline__ void async_ld16(const void* g, void* l){
  __builtin_amdgcn_global_load_lds(
      (__attribute__((address_space(1))) void*)(uintptr_t)g,
      (__attribute__((address_space(3))) void*)l,
      16, 0, 0);
}

// ---------------- fp32 -> bf16 (activations AND weights), grid-stride ----------------
__global__ __launch_bounds__(256) void cvt_f32_bf16(const float* __restrict__ in,
                                                    unsigned short* __restrict__ out, int n4){
  const int stride = gridDim.x * 256;
  for (int i = blockIdx.x * 256 + threadIdx.x; i < n4; i += stride){
    float4 v = ((const float4*)in)[i];
    uint2 o;
    o.x = pack2(v.x, v.y);
    o.y = pack2(v.z, v.w);
    ((uint2*)out)[i] = o;
  }
}

// ---------------- GEMM: C[m, v] = sum_k A[m,k]*W[v,k] + bias[v], all bf16 inputs ----------------
// Tile 128x128x32, 256 threads = 4 waves, each wave 64x64 (4x4 MFMA 16x16x32).
// Both operands staged via global_load_lds (linear LDS dest); XOR swizzle realized by
// pre-swizzling the GLOBAL source address (m173 pattern), swizzled ds_read on the way out.
//
// Grid is 1-D, size 8*NV (NV = v-strips). XCD-ownership mapping (HW: XCD = blockIdx % 8):
//   x = f&7 (XCD), k = f>>3 (per-XCD slot), G = NV>>3.
//   main (k < 8G):  g=k>>3, m-tile = k&7, v = (G-1-g)*8 + x   (descending v!)
//   tail (k >= 8G): v = k, m-tile = x                         (the NV%8 leftover strips)
// => the 8 m-sharers of each W strip are ADJACENT SLOTS ON ONE XCD (misses merge in that
//    XCD's L2; each W line fetched by exactly one XCD), and v descends so the GEMM reads
//    the newest-written (LLC-hot) W rows first, breaking the LRU sequential-scan pathology
//    of reader-follows-writer when Wbf ~ LLC size. Bijective for any NV.
__global__ __launch_bounds__(256, 4) void gemm_logits(
    const unsigned short* __restrict__ A,   // [NTOK, K] bf16
    const unsigned short* __restrict__ W,   // [rows, K] bf16 (chunk base)
    const float* __restrict__ bias,         // chunk base
    unsigned short* __restrict__ C,         // chunk base, row stride VOCAB
    int K)
{
  __shared__ unsigned short lds[2][2][128 * 32];   // [buf][A/B][8KB], 32 KiB total

  const int tid  = threadIdx.x;
  const int lane = tid & 63;
  const int wave = tid >> 6;

  const int f  = blockIdx.x;
  const int NV = gridDim.x >> 3;
  const int G  = NV >> 3;
  const int x  = f & 7;
  const int k  = f >> 3;
  int m128, v;
  if (k < (G << 3)){
    const int g = k >> 3;
    m128 = k & 7;
    v = ((G - 1 - g) << 3) + x;
  } else {
    v = k;
    m128 = x;
  }
  const int m0 = m128 * 128;
  const int v0 = v * 128;

  const int wm = (wave >> 1) * 64;
  const int wn = (wave & 1) * 64;

  // ---- staging: 2 x 16B per thread per operand; inverse-swizzled global source ----
  int ldsoff[2];                    // wave-uniform LDS byte base per instruction
  const unsigned short* gA[2];
  const unsigned short* gW[2];
#pragma unroll
  for (int q = 0; q < 2; ++q){
    const int s    = (wave * 2 + q) * 64 + lane;   // 16B slot index this lane fills
    const int prow = s >> 3;
    const int slot = (s & 7) ^ (prow & 7);         // inverse of the XOR swizzle
    const int row  = (prow << 1) | (slot >> 2);
    const int col  = (slot & 3) * 8;               // bf16 elements
    gA[q] = A + (size_t)(m0 + row) * K + col;
    gW[q] = W + (size_t)(v0 + row) * K + col;
    ldsoff[q] = (wave * 2 + q) * 1024;             // lane*16 added by HW
  }

  // ---- fragment read offsets (swizzled), loop-invariant ----
  const int ar = lane & 15, kq = lane >> 4;
  int offA[4], offB[4];
#pragma unroll
  for (int i = 0; i < 4; ++i){
    int row  = wm + i * 16 + ar;
    int prow = row >> 1;
    int slot = (((row & 1) << 2) | kq) ^ (prow & 7);
    offA[i] = prow * 128 + slot * 16;
    row  = wn + i * 16 + ar;
    prow = row >> 1;
    slot = (((row & 1) << 2) | kq) ^ (prow & 7);
    offB[i] = prow * 128 + slot * 16;
  }

  const f32x4 zero = {0.f, 0.f, 0.f, 0.f};
  f32x4 acc[4][4];
#pragma unroll
  for (int i = 0; i < 4; i++)
#pragma unroll
    for (int j = 0; j < 4; j++) acc[i][j] = zero;

  auto stage = [&](int buf, int k0){
#pragma unroll
    for (int q = 0; q < 2; ++q){
      async_ld16(gA[q] + k0, (char*)(&lds[buf][0][0]) + ldsoff[q]);
      async_ld16(gW[q] + k0, (char*)(&lds[buf][1][0]) + ldsoff[q]);
    }
  };

  const int NT = K >> 5;
  stage(0, 0);
  __syncthreads();                      // compiler drains vmcnt(0) before s_barrier
  int cur = 0;
  for (int kt = 0; kt < NT; ++kt){
    if (kt + 1 < NT) stage(cur ^ 1, (kt + 1) << 5);   // async loads overlap this tile's compute
    const char* pa = (const char*)(&lds[cur][0][0]);
    const char* pb = (const char*)(&lds[cur][1][0]);
    bf16x8 af[4], bfr[4];
#pragma unroll
    for (int i = 0; i < 4; ++i){
      af[i]  = *(const bf16x8*)(pa + offA[i]);
      bfr[i] = *(const bf16x8*)(pb + offB[i]);
    }
#pragma unroll
    for (int i = 0; i < 4; ++i)
#pragma unroll
      for (int j = 0; j < 4; ++j)
        acc[i][j] = __builtin_amdgcn_mfma_f32_16x16x32_bf16(af[i], bfr[j], acc[i][j], 0, 0, 0);
    __syncthreads();                    // drains next-tile loads; all waves done with buf[cur]
    cur ^= 1;
  }

  // epilogue: C/D layout col = lane&15, row = (lane>>4)*4 + reg  [m89-verified]
  const int rq = lane >> 4;
#pragma unroll
  for (int j = 0; j < 4; j++){
    const int vv = v0 + wn + j * 16 + ar;
    const float bv = bias[vv];
#pragma unroll
    for (int i = 0; i < 4; i++){
      const int mbase = m0 + wm + i * 16 + rq * 4;
#pragma unroll
      for (int r = 0; r < 4; r++){
        C[(size_t)(mbase + r) * VOCAB + vv] = f2bf(acc[i][j][r] + bv);
      }
    }
  }
}

// ---------------- fused tail: both LSEs + JSD + CE in ONE pass over HBM ----------------
// Per block (one token row): stage both 64KB bf16 logit rows in LDS (128KB => 1 block/CU),
// then 3 LDS passes: max(s,t) -> expsum(s,t) -> jsd+ce. Saves 2 dispatches and 2/3 of the
// global re-reads vs row_stats x2 + jsd_ce.
__device__ __forceinline__ float jsd_term(float sl, float tl, float ls, float lt){
  float slp = sl - ls, tlp = tl - lt;
  float sp = __expf(slp), tp = __expf(tlp);
  float lm = __logf(0.5f * (sp + tp));
  return 0.5f * (tp * (tlp - lm) + sp * (slp - lm));  // BETA = 0.5
}

__global__ __launch_bounds__(256, 1) void fused_loss(
    const unsigned short* __restrict__ Ls, const unsigned short* __restrict__ Lt,
    const int* __restrict__ labels, float* __restrict__ out)
{
  __shared__ unsigned short sS[VOCAB];   // 64000 B
  __shared__ unsigned short sT[VOCAB];   // 64000 B
  __shared__ float r0[4], r1[4];

  const int row = blockIdx.x;
  const int tid = threadIdx.x;
  const uint4* ps = (const uint4*)(Ls + (size_t)row * VOCAB);
  const uint4* pt = (const uint4*)(Lt + (size_t)row * VOCAB);
  uint4* ds = (uint4*)sS;
  uint4* dt = (uint4*)sT;
  for (int i = tid; i < VOCAB / 8; i += 256){ ds[i] = ps[i]; dt[i] = pt[i]; }
  __syncthreads();

  // ---- pass 1: row maxes (both sides) ----
  float ms = -3.0e38f, mt = -3.0e38f;
  for (int i = tid; i < VOCAB / 8; i += 256){
    uint4 us = ds[i], ut = dt[i];
    ms = fmaxf(ms, fmaxf(fmaxf(fmaxf(blo(us.x), bhi(us.x)), fmaxf(blo(us.y), bhi(us.y))),
                         fmaxf(fmaxf(blo(us.z), bhi(us.z)), fmaxf(blo(us.w), bhi(us.w)))));
    mt = fmaxf(mt, fmaxf(fmaxf(fmaxf(blo(ut.x), bhi(ut.x)), fmaxf(blo(ut.y), bhi(ut.y))),
                         fmaxf(fmaxf(blo(ut.z), bhi(ut.z)), fmaxf(blo(ut.w), bhi(ut.w)))));
  }
#pragma unroll
  for (int off = 1; off < 64; off <<= 1){
    ms = fmaxf(ms, __shfl_xor(ms, off));
    mt = fmaxf(mt, __shfl_xor(mt, off));
  }
  if ((tid & 63) == 0){ r0[tid >> 6] = ms; r1[tid >> 6] = mt; }
  __syncthreads();
  ms = fmaxf(fmaxf(r0[0], r0[1]), fmaxf(r0[2], r0[3]));
  mt = fmaxf(fmaxf(r1[0], r1[1]), fmaxf(r1[2], r1[3]));
  __syncthreads();

  // ---- pass 2: exp sums ----
  float ss = 0.f, st = 0.f;
  for (int i = tid; i < VOCAB / 8; i += 256){
    uint4 us = ds[i], ut = dt[i];
    ss += __expf(blo(us.x) - ms) + __expf(bhi(us.x) - ms)
        + __expf(blo(us.y) - ms) + __expf(bhi(us.y) - ms)
        + __expf(blo(us.z) - ms) + __expf(bhi(us.z) - ms)
        + __expf(blo(us.w) - ms) + __expf(bhi(us.w) - ms);
    st += __expf(blo(ut.x) - mt) + __expf(bhi(ut.x) - mt)
        + __expf(blo(ut.y) - mt) + __expf(bhi(ut.y) - mt)
        + __expf(blo(ut.z) - mt) + __expf(bhi(ut.z) - mt)
        + __expf(blo(ut.w) - mt) + __expf(bhi(ut.w) - mt);
  }
#pragma unroll
  for (int off = 1; off < 64; off <<= 1){
    ss += __shfl_xor(ss, off);
    st += __shfl_xor(st, off);
  }
  if ((tid & 63) == 0){ r0[tid >> 6] = ss; r1[tid >> 6] = st; }
  __syncthreads();
  const float ls = ms + __logf(r0[0] + r0[1] + r0[2] + r0[3]);
  const float lt = mt + __logf(r1[0] + r1[1] + r1[2] + r1[3]);
  __syncthreads();

  // ---- pass 3: JSD (+ CE on thread 0) ----
  float acc = 0.f;
  for (int i = tid; i < VOCAB / 8; i += 256){
    uint4 us = ds[i], ut = dt[i];
    acc += jsd_term(blo(us.x), blo(ut.x), ls, lt) + jsd_term(bhi(us.x), bhi(ut.x), ls, lt);
    acc += jsd_term(blo(us.y), blo(ut.y), ls, lt) + jsd_term(bhi(us.y), bhi(ut.y), ls, lt);
    acc += jsd_term(blo(us.z), blo(ut.z), ls, lt) + jsd_term(bhi(us.z), bhi(ut.z), ls, lt);
    acc += jsd_term(blo(us.w), blo(ut.w), ls, lt) + jsd_term(bhi(us.w), bhi(ut.w), ls, lt);
  }
#pragma unroll
  for (int off = 1; off < 64; off <<= 1) acc += __shfl_xor(acc, off);
  if ((tid & 63) == 0) r0[tid >> 6] = acc;
  __syncthreads();
  if (tid == 0){
    float tot = r0[0] + r0[1] + r0[2] + r0[3];
    float res = tot * (0.5f / (float)NTOK);          // WEIGHT_SOFT * jsd / N
    int lab = labels[row];
    if (lab != -100){
      float sl_lab = __uint_as_float((unsigned)sS[lab] << 16);
      res += (ls - sl_lab) * (0.5f / (float)NTOK);   // WEIGHT_HARD * nll / N
    }
    atomicAdd(out, res);
  }
}

extern "C" void kernel_launch(void* const* d_in, const int* in_sizes, int n_in,
                              void* d_out, int out_size, void* d_ws, size_t ws_size,
                              hipStream_t stream){
  (void)in_sizes; (void)n_in; (void)out_size;
  const float* s_in = (const float*)d_in[0];
  const float* s_w  = (const float*)d_in[1];
  const float* t_in = (const float*)d_in[2];
  const float* t_w  = (const float*)d_in[3];
  const int*   lab  = (const int*)d_in[4];
  const float* s_b  = (const float*)d_in[5];
  const float* t_b  = (const float*)d_in[6];
  float* out = (float*)d_out;

  char* ws = (char*)d_ws;
  size_t off = 0;
  auto alloc = [&](size_t b){ void* p = ws + off; off += (b + 255) & ~(size_t)255; return p; };
  unsigned short* As_bf = (unsigned short*)alloc((size_t)NTOK * HS * 2);
  unsigned short* At_bf = (unsigned short*)alloc((size_t)NTOK * HT * 2);
  unsigned short* Ls    = (unsigned short*)alloc((size_t)NTOK * VOCAB * 2);
  unsigned short* Lt    = (unsigned short*)alloc((size_t)NTOK * VOCAB * 2);
  unsigned short* Wbf = (unsigned short*)(ws + off);          // rest of workspace: bf16 W
  const size_t rem = (ws_size > off) ? (ws_size - off) : 0;

  hipMemsetAsync(d_out, 0, sizeof(float), stream);  // d_out is poisoned before each launch

  cvt_f32_bf16<<<NTOK * HS / 4 / 256, 256, 0, stream>>>(s_in, As_bf, NTOK * HS / 4);
  cvt_f32_bf16<<<NTOK * HT / 4 / 256, 256, 0, stream>>>(t_in, At_bf, NTOK * HT / 4);

  // per-side: convert the FULL W to bf16 (one pass), then one full-grid bf16 GEMM
  // (1-D grid, XCD-ownership + descending-v mapping inside the kernel).
  auto side = [&](const unsigned short* Abf, const float* Wf, const float* bf,
                  unsigned short* L, int K){
    const size_t need = (size_t)VOCAB * K * 2;
    if (rem >= need){
      int n4 = (int)((size_t)VOCAB * K / 4);
      int cb = (n4 + 255) / 256; if (cb > 8192) cb = 8192;
      cvt_f32_bf16<<<cb, 256, 0, stream>>>(Wf, Wbf, n4);
      gemm_logits<<<8 * (VOCAB / 128), 256, 0, stream>>>(Abf, Wbf, bf, L, K);
    } else {
      int crows = 8192;                                  // fallback: chunked
      size_t maxr = rem / ((size_t)K * 2);
      if ((size_t)crows > maxr) crows = (int)(maxr & ~(size_t)127);
      if (crows < 128) crows = 128;
      for (int vb = 0; vb < VOCAB; vb += crows){
        int rows = VOCAB - vb; if (rows > crows) rows = crows;
        int n4 = (int)((size_t)rows * K / 4);
        int cb = (n4 + 255) / 256; if (cb > 8192) cb = 8192;
        cvt_f32_bf16<<<cb, 256, 0, stream>>>(Wf + (size_t)vb * K, Wbf, n4);
        gemm_logits<<<8 * (rows / 128), 256, 0, stream>>>(Abf, Wbf, bf + vb, L + vb, K);
      }
    }
  };
  side(As_bf, s_w, s_b, Ls, HS);
  side(At_bf, t_w, t_b, Lt, HT);

  fused_loss<<<NTOK, 256, 0, stream>>>(Ls, Lt, lab, out);
}